// Round 3
// baseline (219.135 us; speedup 1.0000x reference)
//
#include <hip/hip_runtime.h>

// Performer linear attention, 32x32x16 MFMA, register-resident features.
// n=2, l=2048, h=8, e=64, m=2048. Dtype runtime-detected (bf16 confirmed).
// ws (floats): flag[16] | c_k[32768] | c_q[32768] | ksum01[2][32768] (reused as pad[2][32768])
//   | kvf01[2][16][64][2048] f32 (reused as po[2][32768][64]) | ksumW[32768] | kvT bf16[16][64][2048]
// R9: barrier-drain round. __syncthreads() emits s_waitcnt vmcnt(0) before s_barrier ->
//     every iteration waited for its own prefetch loads (m97 ceiling mechanism); this is
//     why R7 (occupancy) and R8 (L2-residency, FETCH 70->17MB) didn't move time.
//     Replace main-loop barriers with raw {s_waitcnt lgkmcnt(0); s_barrier} so register
//     prefetch stays in flight across barriers; compiler's counted vmcnt before the
//     ds_write staging is the only vmem wait (one full iteration of slack).

#define LL 2048
#define HH 8
#define MM 2048
#define ROWSTR 512  // HH*64

#define NORMC 0.35355339059327373f   // 64^-0.25
#define LOG2E 1.4426950408889634f
#define NORMC2 (NORMC * LOG2E)
#define RATIO 0.022097086912079608f  // 2048^-0.5
#define KEPS 1e-4f
#define REPS (RATIO * KEPS)
#define EPSD 1e-6f

#define KVSPLIT 2097152
#define RSPLIT 32768

typedef __attribute__((ext_vector_type(8))) short short8;
typedef __attribute__((ext_vector_type(16))) float f32x16;

#define MFMA32(a, b, c) __builtin_amdgcn_mfma_f32_32x32x16_bf16((a), (b), (c), 0, 0, 0)

// LDS-only workgroup barrier: drains lgkmcnt (cross-wave LDS produce/consume needs it)
// but leaves global register-prefetch loads in flight (no vmcnt drain).
__device__ __forceinline__ void wg_barrier_lds() {
    asm volatile("s_waitcnt lgkmcnt(0)" ::: "memory");
    __builtin_amdgcn_s_barrier();
    __builtin_amdgcn_sched_barrier(0);
}

__device__ __forceinline__ f32x16 zero16() {
    f32x16 v;
    #pragma unroll
    for (int i = 0; i < 16; ++i) v[i] = 0.f;
    return v;
}
__device__ __forceinline__ unsigned short f2bf(float f) {  // RNE
    union { float f; unsigned int u; } v; v.f = f;
    unsigned int r = v.u + 0x7fffu + ((v.u >> 16) & 1u);
    return (unsigned short)(r >> 16);
}
__device__ __forceinline__ unsigned int pk2(float lo, float hi) {  // trunc pack
    return __builtin_amdgcn_perm(__float_as_uint(hi), __float_as_uint(lo), 0x07060302u);
}
__device__ __forceinline__ float bf2f(unsigned short u) {
    union { unsigned int ui; float f; } v; v.ui = ((unsigned int)u) << 16; return v.f;
}

// ---- 64x64 tile staging into LDS [64][72] bf16 ----
template <bool BF16>
__device__ __forceinline__ void tile_load(const void* src, size_t base, size_t rstride,
                                          int t, uint4& A, uint4& B) {
    const int row = t >> 2, c16 = (t & 3) * 16;
    if (BF16) {
        const unsigned short* p = (const unsigned short*)src + base + (size_t)row * rstride + c16;
        A = *(const uint4*)p;
        B = *(const uint4*)(p + 8);
    } else {
        const float* p = (const float*)src + base + (size_t)row * rstride + c16;
        float4 f0 = ((const float4*)p)[0], f1 = ((const float4*)p)[1];
        float4 f2 = ((const float4*)p)[2], f3 = ((const float4*)p)[3];
        A.x = pk2(f0.x, f0.y); A.y = pk2(f0.z, f0.w);
        A.z = pk2(f1.x, f1.y); A.w = pk2(f1.z, f1.w);
        B.x = pk2(f2.x, f2.y); B.y = pk2(f2.z, f2.w);
        B.z = pk2(f3.x, f3.y); B.w = pk2(f3.z, f3.w);
    }
}
__device__ __forceinline__ void tile_store72(unsigned short* D, int t, uint4 A, uint4 B) {
    const int row = t >> 2, c16 = (t & 3) * 16;
    *(uint4*)&D[row * 72 + c16] = A;
    *(uint4*)&D[row * 72 + c16 + 8] = B;
}

// ---- V transpose staging into LDS [64e][72] ----
template <bool BF16>
__device__ __forceinline__ void vt_load(const void* V, size_t base, int t, uint4& A, uint4& B) {
    const int s0 = (t & 31) * 2, e0 = (t >> 5) * 8;
    if (BF16) {
        const unsigned short* p = (const unsigned short*)V + base + (size_t)s0 * ROWSTR + e0;
        A = *(const uint4*)p;
        B = *(const uint4*)(p + ROWSTR);
    } else {
        const float* p = (const float*)V + base + (size_t)s0 * ROWSTR + e0;
        float4 f0 = ((const float4*)p)[0], f1 = ((const float4*)p)[1];
        const float* q = p + ROWSTR;
        float4 g0 = ((const float4*)q)[0], g1 = ((const float4*)q)[1];
        A.x = pk2(f0.x, f0.y); A.y = pk2(f0.z, f0.w);
        A.z = pk2(f1.x, f1.y); A.w = pk2(f1.z, f1.w);
        B.x = pk2(g0.x, g0.y); B.y = pk2(g0.z, g0.w);
        B.z = pk2(g1.x, g1.y); B.w = pk2(g1.z, g1.w);
    }
}
__device__ __forceinline__ void vt_store72(unsigned short* VT, int t, uint4 A, uint4 B) {
    const int s0 = (t & 31) * 2, e0 = (t >> 5) * 8;
    const unsigned ua[4] = {A.x, A.y, A.z, A.w}, ub[4] = {B.x, B.y, B.z, B.w};
    #pragma unroll
    for (int i = 0; i < 4; ++i) {
        *(unsigned*)&VT[(e0 + 2 * i) * 72 + s0] = (ua[i] & 0xFFFFu) | (ub[i] << 16);
        *(unsigned*)&VT[(e0 + 2 * i + 1) * 72 + s0] = (ua[i] >> 16) | (ub[i] & 0xFFFF0000u);
    }
}

// ---- D-layout -> B-operand exchange (half-wave) ----
__device__ __forceinline__ short8 xfrag(const unsigned int pd[8], int cp, int hi) {
    const unsigned int s0 = hi ? pd[4 * cp + 0] : pd[4 * cp + 2];
    const unsigned int s1 = hi ? pd[4 * cp + 1] : pd[4 * cp + 3];
    const unsigned int r0 = (unsigned int)__shfl_xor((int)s0, 32);
    const unsigned int r1 = (unsigned int)__shfl_xor((int)s1, 32);
    union { unsigned int u[4]; short8 s; } v;
    v.u[0] = hi ? r0 : pd[4 * cp + 0];
    v.u[1] = hi ? r1 : pd[4 * cp + 1];
    v.u[2] = hi ? pd[4 * cp + 2] : r0;
    v.u[3] = hi ? pd[4 * cp + 3] : r1;
    return v.s;
}

// ---------------- dtype detection ----------------
__global__ void LinearAttention_15985868276494_detect(const unsigned short* __restrict__ P,
                                                      float* __restrict__ flag) {
    if (threadIdx.x == 0) {
        int sane = 1;
        #pragma unroll
        for (int i = 0; i < 16; ++i) {
            const unsigned e = (P[2 * i] >> 7) & 0xFF;
            if (e < 101 || e > 141) sane = 0;
        }
        *flag = sane ? 1.0f : 0.0f;
    }
}

// ---------------- stats: c[nh][l] * log2e, 64 rows per block, 32 x 64-m tiles ----------------
template <bool BF16>
__device__ void stats_impl(const void* X, const void* P, float* cws,
                           unsigned short* Xs, unsigned short* Ps, float* red) {
    const int t = threadIdx.x;
    const int w = t >> 6, ln = t & 31, hi = (t >> 5) & 1;
    const int rstrip = w & 1, mstrip = w >> 1;
    const int row_base = blockIdx.x * 64;

    uint4 a0, b0;
    tile_load<BF16>(X, (size_t)row_base * 64, 64, t, a0, b0);
    tile_store72(Xs, t, a0, b0);
    tile_load<BF16>(P, 0, 64, t, a0, b0);
    tile_store72(Ps, t, a0, b0);
    uint4 pA, pB;
    tile_load<BF16>(P, (size_t)64 * 64, 64, t, pA, pB);
    wg_barrier_lds();

    short8 xb[4];
    #pragma unroll
    for (int c = 0; c < 4; ++c)
        xb[c] = *(const short8*)&Xs[(32 * rstrip + ln) * 72 + 16 * c + 8 * hi];

    float rmax = -3e38f;
    for (int i = 0; i < 32; ++i) {
        const int cur = i & 1;
        unsigned short* Pc = Ps + cur * 4608;
        f32x16 acc = zero16();
        #pragma unroll
        for (int c = 0; c < 4; ++c) {
            const short8 af = *(const short8*)&Pc[(32 * mstrip + ln) * 72 + 16 * c + 8 * hi];
            acc = MFMA32(af, xb[c], acc);
        }
        if (i + 1 < 32) {
            tile_store72(Ps + (cur ^ 1) * 4608, t, pA, pB);
            if (i + 2 < 32)
                tile_load<BF16>(P, (size_t)((i + 2) * 64) * 64, 64, t, pA, pB);
        }
        #pragma unroll
        for (int r = 0; r < 16; ++r) rmax = fmaxf(rmax, acc[r]);
        wg_barrier_lds();
    }
    rmax = fmaxf(rmax, __shfl_xor(rmax, 32));
    if (hi == 0) red[w * 32 + ln] = rmax;
    wg_barrier_lds();
    if (t < 64) {
        const int rs = t >> 5;
        const float rm = fmaxf(red[rs * 32 + (t & 31)], red[(rs + 2) * 32 + (t & 31)]);
        float s2 = 0.f;
        #pragma unroll
        for (int c = 0; c < 64; c += 8) {
            uint4 u = *(const uint4*)&Xs[t * 72 + c];
            const unsigned int ua[4] = {u.x, u.y, u.z, u.w};
            #pragma unroll
            for (int i = 0; i < 4; ++i) {
                const float lo = bf2f((unsigned short)(ua[i] & 0xFFFF));
                const float hv = bf2f((unsigned short)(ua[i] >> 16));
                s2 = fmaf(lo, lo, s2); s2 = fmaf(hv, hv, s2);
            }
        }
        const int rg = row_base + t;
        const int n = rg >> 14, l = (rg >> 3) & 2047, h = rg & 7;
        cws[(size_t)((n << 3) | h) * LL + l] =
            (NORMC * rm + (0.5f * NORMC * NORMC) * s2) * LOG2E;
    }
}

__global__ __launch_bounds__(256, 4) void LinearAttention_15985868276494_stats(
        const void* K, const void* Q, const void* P, const float* flag,
        float* c_k, float* c_q) {
    __shared__ unsigned short Xs[64 * 72];
    __shared__ unsigned short Ps[2 * 64 * 72];
    __shared__ float red[128];
    const void* X = (blockIdx.y == 0) ? K : Q;
    float* cws = (blockIdx.y == 0) ? c_k : c_q;
    if (*flag != 0.f) stats_impl<true>(X, P, cws, Xs, Ps, red);
    else stats_impl<false>(X, P, cws, Xs, Ps, red);
}

// ---------------- kv: partial kvf[sp][nh][e][m] f32, ksum01 ----------------
// Grid 1024 linear, XCD-swizzled: bid = (g&7) + 8*(4*mt + (g>>3)), g = nh*2+sp.
// All 32 mt-blocks of a (nh,sp) group land on XCD g%8 -> K/V strip L2-resident.
// LDS: Ks[2][64*72] | VT[2][64*72] | cks[2][64]  (P tile aliases Ks buf1; fin aliases all)
template <bool BF16>
__device__ void kv_impl(const void* K, const void* V, const void* P, const float* cws,
                        float* kvf01, float* ksum01, char* smem) {
    unsigned short* Ks = (unsigned short*)smem;            // [2][64*72]
    unsigned short* VT = (unsigned short*)(smem + 18432);  // [2][64*72]
    float* cks = (float*)(smem + 36864);                   // [2][64]
    float* fin = (float*)smem;                             // [4*64*33], aliases Ks+VT

    const int t = threadIdx.x;
    const int w = t >> 6, ln = t & 31, hi = (t >> 5) & 1;
    const int sstrip = w & 1, mstrip = w >> 1;
    // XCD swizzle decode
    const int bid = blockIdx.x;
    const int xcd = bid & 7, rr = bid >> 3;
    const int ghi = rr & 3, mt = rr >> 2;
    const int g = (ghi << 3) | xcd;
    const int nh = g >> 1, sp = g & 1;
    const int n = nh >> 3, h = nh & 7;
    const size_t xbase = (size_t)n * (LL * ROWSTR) + (size_t)h * 64;
    const int st0 = sp * 16;

    unsigned short* Ps = Ks + 4608;  // P tile aliases K double-buffer slot 1
    {
        uint4 pa, pbv;
        tile_load<BF16>(P, (size_t)(mt * 64) * 64, 64, t, pa, pbv);
        tile_store72(Ps, t, pa, pbv);
    }
    uint4 kA, kB, vA, vB; float ckr = 0.f;
    tile_load<BF16>(K, xbase + (size_t)(st0 * 64) * ROWSTR, ROWSTR, t, kA, kB);
    vt_load<BF16>(V, xbase + (size_t)(st0 * 64) * ROWSTR, t, vA, vB);
    if (t < 64) ckr = cws[(size_t)nh * LL + st0 * 64 + t];
    tile_store72(Ks, t, kA, kB);
    vt_store72(VT, t, vA, vB);
    if (t < 64) cks[t] = ckr;
    tile_load<BF16>(K, xbase + (size_t)((st0 + 1) * 64) * ROWSTR, ROWSTR, t, kA, kB);
    vt_load<BF16>(V, xbase + (size_t)((st0 + 1) * 64) * ROWSTR, t, vA, vB);
    if (t < 64) ckr = cws[(size_t)nh * LL + (st0 + 1) * 64 + t];
    wg_barrier_lds();

    short8 pb[4];
    #pragma unroll
    for (int c = 0; c < 4; ++c)
        pb[c] = *(const short8*)&Ps[(32 * mstrip + ln) * 72 + 16 * c + 8 * hi];
    wg_barrier_lds();  // pb read complete before iter0 overwrites Ps(=Ks1)
    const short8 ones = {0x3F80, 0x3F80, 0x3F80, 0x3F80, 0x3F80, 0x3F80, 0x3F80, 0x3F80};

    f32x16 akv0 = zero16(), akv1 = zero16(), aks = zero16();

    for (int i = 0; i < 16; ++i) {
        const int cur = i & 1;
        unsigned short* Kc = Ks + cur * 4608;
        unsigned short* Vc = VT + cur * 4608;
        const float* cc = cks + cur * 64;
        // gemm1 first: ds_reads issue right after the barrier
        f32x16 D = zero16();
        #pragma unroll
        for (int c = 0; c < 4; ++c) {
            const short8 af = *(const short8*)&Kc[(32 * sstrip + ln) * 72 + 16 * c + 8 * hi];
            D = MFMA32(af, pb[c], D);
        }
        // staging: store tile i+1 (counted vmcnt wait, 1 iter of slack), prefetch tile i+2
        if (i + 1 < 16) {
            tile_store72(Ks + (cur ^ 1) * 4608, t, kA, kB);
            vt_store72(VT + (cur ^ 1) * 4608, t, vA, vB);
            if (t < 64) cks[(cur ^ 1) * 64 + t] = ckr;
            if (i + 2 < 16) {
                const int st = st0 + i + 2;
                tile_load<BF16>(K, xbase + (size_t)(st * 64) * ROWSTR, ROWSTR, t, kA, kB);
                vt_load<BF16>(V, xbase + (size_t)(st * 64) * ROWSTR, t, vA, vB);
                if (t < 64) ckr = cws[(size_t)nh * LL + st * 64 + t];
            }
        }
        // exp2 (c pre-scaled by log2e; varies with s = row)
        unsigned int pd[8];
        #pragma unroll
        for (int gIdx = 0; gIdx < 4; ++gIdx) {
            const float4 c4 = *(const float4*)&cc[32 * sstrip + 8 * gIdx + 4 * hi];
            const float ca[4] = {c4.x, c4.y, c4.z, c4.w};
            float f[4];
            #pragma unroll
            for (int b = 0; b < 4; ++b) {
                const float arg = fminf(fmaf(D[4 * gIdx + b], NORMC2, -ca[b]), 0.f);
                f[b] = fmaf(__builtin_amdgcn_exp2f(arg), RATIO, REPS);
            }
            pd[2 * gIdx] = pk2(f[0], f[1]);
            pd[2 * gIdx + 1] = pk2(f[2], f[3]);
        }
        // gemm2: akv[e][m] += V^T . F   (register F via exchange)
        #pragma unroll
        for (int cp = 0; cp < 2; ++cp) {
            const short8 bf = xfrag(pd, cp, hi);
            const int scol = 32 * sstrip + 16 * cp + 8 * hi;
            const short8 v0 = *(const short8*)&Vc[ln * 72 + scol];
            const short8 v1 = *(const short8*)&Vc[(32 + ln) * 72 + scol];
            akv0 = MFMA32(v0, bf, akv0);
            akv1 = MFMA32(v1, bf, akv1);
            aks = MFMA32(ones, bf, aks);
        }
        wg_barrier_lds();
    }
    // cross-sstrip reduce + store (fin stride 33: bank-conflict-free)
    {
        const int slot = (w * 64 + (t & 63)) * 33;
        #pragma unroll
        for (int r = 0; r < 16; ++r) fin[slot + r] = akv0[r];
        #pragma unroll
        for (int r = 0; r < 16; ++r) fin[slot + 16 + r] = akv1[r];
        fin[slot + 32] = aks[0];
    }
    wg_barrier_lds();
    {
        const int e = t >> 2;
        const int t16 = e >> 5, e5 = e & 31;
        const int hi_s = (e5 >> 2) & 1;
        const int reg = 16 * t16 + (e5 & 3) + 4 * (e5 >> 3);
        float* dst = kvf01 + (size_t)sp * KVSPLIT + (size_t)nh * (64 * MM)
                   + (size_t)e * MM + mt * 64 + (t & 3) * 16;
        #pragma unroll
        for (int jq = 0; jq < 4; ++jq) {
            float o[4];
            #pragma unroll
            for (int b = 0; b < 4; ++b) {
                const int m_local = (t & 3) * 16 + 4 * jq + b;
                const int ms = m_local >> 5;
                const int lane_s = hi_s * 32 + (m_local & 31);
                o[b] = fin[((2 * ms) * 64 + lane_s) * 33 + reg]
                     + fin[((2 * ms + 1) * 64 + lane_s) * 33 + reg];
            }
            *(float4*)&dst[4 * jq] = make_float4(o[0], o[1], o[2], o[3]);
        }
        if (t < 64) {
            const int ms = t >> 5;
            const float val = fin[((2 * ms) * 64 + (t & 31)) * 33 + 32]
                            + fin[((2 * ms + 1) * 64 + (t & 31)) * 33 + 32];
            ksum01[(size_t)sp * RSPLIT + (size_t)nh * MM + mt * 64 + t] = val;
        }
    }
}

__global__ __launch_bounds__(256, 4) void LinearAttention_15985868276494_kv(
        const void* K, const void* V, const void* P, const float* flag,
        const float* cws, float* kvf01, float* ksum01) {
    extern __shared__ char smem_kv[];
    if (*flag != 0.f) kv_impl<true>(K, V, P, cws, kvf01, ksum01, smem_kv);
    else kv_impl<false>(K, V, P, cws, kvf01, ksum01, smem_kv);
}

// ---------------- reduce: kvT bf16 = split0+split1 (element-wise); ksumW ----------------
__global__ __launch_bounds__(256) void LinearAttention_15985868276494_reduce(
        const float* __restrict__ kvf01, const float* __restrict__ ksum01,
        unsigned short* __restrict__ kvT, float* __restrict__ ksumW) {
    const int gid = blockIdx.x * 256 + threadIdx.x;
    const size_t i4 = (size_t)gid * 4;
    const float4 a = *(const float4*)&kvf01[i4];
    const float4 b = *(const float4*)&kvf01[KVSPLIT + i4];
    uint2 o;
    o.x = (unsigned)f2bf(a.x + b.x) | ((unsigned)f2bf(a.y + b.y) << 16);
    o.y = (unsigned)f2bf(a.z + b.z) | ((unsigned)f2bf(a.w + b.w) << 16);
    *(uint2*)&kvT[i4] = o;
    if (blockIdx.x < 32) {
        const float4 c = *(const float4*)&ksum01[i4];
        const float4 d = *(const float4*)&ksum01[RSPLIT + i4];
        *(float4*)&ksumW[i4] = make_float4(c.x + d.x, c.y + d.y, c.z + d.z, c.w + d.w);
    }
}

// ---------------- out (partial over m-half sp): po f32, pad f32 ----------------
// Grid 1024 linear, XCD-swizzled like kv: all 32 lb-blocks of (nh,sp) on one XCD
// -> kvT half-strip + P half L2-resident.
// LDS: Ps[2][64*72] | KVs[2][64*72] | kss[2][64]  (Q tile aliases Ps buf1; fin aliases all)
template <bool BF16>
__device__ void out_impl(const void* Q, const void* P, const float* cqw,
                         const unsigned short* kvT, const float* ksum,
                         float* po, float* pad, char* smem) {
    unsigned short* Ps = (unsigned short*)smem;              // [2][64*72]
    unsigned short* KVs = (unsigned short*)(smem + 18432);   // [2][64*72]
    unsigned short* kss = (unsigned short*)(smem + 36864);   // [2][64]
    float* fin = (float*)smem;                               // [4*64*33]

    const int t = threadIdx.x;
    const int w = t >> 6, ln = t & 31, hi = (t >> 5) & 1;
    const int mstrip = w & 1, lstrip = w >> 1;
    // XCD swizzle decode
    const int bid = blockIdx.x;
    const int xcd = bid & 7, rr = bid >> 3;
    const int ghi = rr & 3, lb = rr >> 2;
    const int g = (ghi << 3) | xcd;
    const int nh = g >> 1, sp = g & 1;
    const int n = nh >> 3, h = nh & 7;
    const size_t qbase = (size_t)n * (LL * ROWSTR) + (size_t)h * 64 + (size_t)(lb * 64) * ROWSTR;
    const size_t kvbase = (size_t)nh * (size_t)(64 * MM);
    const int mt0 = sp * 16;

    unsigned short* Qs = Ps + 4608;  // Q tile aliases P double-buffer slot 1
    {
        uint4 qa, qbv;
        tile_load<BF16>(Q, qbase, ROWSTR, t, qa, qbv);
        tile_store72(Qs, t, qa, qbv);
    }
    uint4 pA, pB, kA, kB; float ksr = 0.f;
    tile_load<BF16>(P, (size_t)(mt0 * 64) * 64, 64, t, pA, pB);
    tile_load<true>(kvT, kvbase + mt0 * 64, MM, t, kA, kB);
    if (t < 64) ksr = ksum[(size_t)nh * MM + mt0 * 64 + t];
    tile_store72(Ps, t, pA, pB);
    tile_store72(KVs, t, kA, kB);
    if (t < 64) kss[t] = f2bf(ksr);
    tile_load<BF16>(P, (size_t)((mt0 + 1) * 64) * 64, 64, t, pA, pB);
    tile_load<true>(kvT, kvbase + (mt0 + 1) * 64, MM, t, kA, kB);
    if (t < 64) ksr = ksum[(size_t)nh * MM + (mt0 + 1) * 64 + t];
    wg_barrier_lds();

    short8 qb[4];
    #pragma unroll
    for (int c = 0; c < 4; ++c)
        qb[c] = *(const short8*)&Qs[(32 * lstrip + ln) * 72 + 16 * c + 8 * hi];
    const float cq = cqw[(size_t)nh * LL + lb * 64 + lstrip * 32 + ln];
    wg_barrier_lds();  // qb read complete before iter0 overwrites Qs(=Ps1)

    f32x16 ao0 = zero16(), ao1 = zero16(), ad = zero16();

    for (int i = 0; i < 16; ++i) {
        const int cur = i & 1;
        unsigned short* Pc = Ps + cur * 4608;
        unsigned short* Kc = KVs + cur * 4608;
        const unsigned short* ksc = kss + cur * 64;
        // gemm1 first
        f32x16 D = zero16();
        #pragma unroll
        for (int c = 0; c < 4; ++c) {
            const short8 af = *(const short8*)&Pc[(32 * mstrip + ln) * 72 + 16 * c + 8 * hi];
            D = MFMA32(af, qb[c], D);
        }
        // staging after gemm1
        if (i + 1 < 16) {
            tile_store72(Ps + (cur ^ 1) * 4608, t, pA, pB);
            tile_store72(KVs + (cur ^ 1) * 4608, t, kA, kB);
            if (t < 64) kss[(cur ^ 1) * 64 + t] = f2bf(ksr);
            if (i + 2 < 16) {
                tile_load<BF16>(P, (size_t)((mt0 + i + 2) * 64) * 64, 64, t, pA, pB);
                tile_load<true>(kvT, kvbase + (mt0 + i + 2) * 64, MM, t, kA, kB);
                if (t < 64) ksr = ksum[(size_t)nh * MM + (mt0 + i + 2) * 64 + t];
            }
        }
        // exp2 (cq pre-scaled by log2e; depends on l = col only)
        unsigned int pd[8];
        #pragma unroll
        for (int gIdx = 0; gIdx < 4; ++gIdx) {
            float f[4];
            #pragma unroll
            for (int b = 0; b < 4; ++b) {
                const float arg = fminf(fmaf(D[4 * gIdx + b], NORMC2, -cq), 0.f);
                f[b] = fmaf(__builtin_amdgcn_exp2f(arg), RATIO, REPS);
            }
            pd[2 * gIdx] = pk2(f[0], f[1]);
            pd[2 * gIdx + 1] = pk2(f[2], f[3]);
        }
        // gemm2: O[e][l] += KV . F ; ad[.][l] += ksum . F
        #pragma unroll
        for (int cp = 0; cp < 2; ++cp) {
            const short8 bf = xfrag(pd, cp, hi);
            const int mcol = 32 * mstrip + 16 * cp + 8 * hi;
            const short8 a0 = *(const short8*)&Kc[ln * 72 + mcol];
            const short8 a1 = *(const short8*)&Kc[(32 + ln) * 72 + mcol];
            const short8 k8 = *(const short8*)&ksc[mcol];
            ao0 = MFMA32(a0, bf, ao0);
            ao1 = MFMA32(a1, bf, ao1);
            ad = MFMA32(k8, bf, ad);
        }
        wg_barrier_lds();
    }
    {
        const int slot = (w * 64 + (t & 63)) * 33;
        #pragma unroll
        for (int r = 0; r < 16; ++r) fin[slot + r] = ao0[r];
        #pragma unroll
        for (int r = 0; r < 16; ++r) fin[slot + 16 + r] = ao1[r];
        fin[slot + 32] = ad[0];
    }
    wg_barrier_lds();
    {
        const int l_local = t >> 2, eg = t & 3;
        const int ls = l_local >> 5, lane_l = l_local & 31;
        const float adt = fin[((2 * ls) * 64 + lane_l) * 33 + 32]
                        + fin[((2 * ls + 1) * 64 + lane_l) * 33 + 32];
        const int l = lb * 64 + l_local;
        const size_t row = (size_t)(n * LL + l) * HH + h;
        if (eg == 0) pad[(size_t)sp * RSPLIT + row] = adt;
        float* dst = po + (size_t)sp * KVSPLIT + row * 64 + eg * 16;
        #pragma unroll
        for (int jq = 0; jq < 4; ++jq) {
            float o[4];
            #pragma unroll
            for (int b = 0; b < 4; ++b) {
                const int e = eg * 16 + 4 * jq + b;
                const int t16 = e >> 5, e5 = e & 31;
                const int hi_s = (e5 >> 2) & 1;
                const int reg = 16 * t16 + (e5 & 3) + 4 * (e5 >> 3);
                const int lane_s = hi_s * 32 + lane_l;
                o[b] = fin[((2 * ls) * 64 + lane_s) * 33 + reg]
                     + fin[((2 * ls + 1) * 64 + lane_s) * 33 + reg];
            }
            *(float4*)&dst[4 * jq] = make_float4(o[0], o[1], o[2], o[3]);
        }
    }
}

__global__ __launch_bounds__(256, 4) void LinearAttention_15985868276494_out(
        const void* Q, const void* P, const float* flag, const float* cqw,
        const unsigned short* kvT, const float* ksum, float* po, float* pad) {
    extern __shared__ char smem_out[];
    if (*flag != 0.f) out_impl<true>(Q, P, cqw, kvT, ksum, po, pad, smem_out);
    else out_impl<false>(Q, P, cqw, kvT, ksum, po, pad, smem_out);
}

// ---------------- out2: combine m-halves, normalize, emit ----------------
__global__ __launch_bounds__(256) void LinearAttention_15985868276494_out2(
        const float* __restrict__ po, const float* __restrict__ pad,
        const float* __restrict__ flag, void* __restrict__ outp) {
    const int gid = blockIdx.x * 256 + threadIdx.x;
    const int row = gid >> 2, eg = gid & 3;
    const float adt = pad[row] + pad[RSPLIT + row];
    const float z = 1.0f / (adt + EPSD);
    const size_t base = (size_t)row * 64 + eg * 16;
    float vals[16];
    #pragma unroll
    for (int q4 = 0; q4 < 4; ++q4) {
        const float4 a = *(const float4*)&po[base + 4 * q4];
        const float4 b = *(const float4*)&po[KVSPLIT + base + 4 * q4];
        vals[4 * q4 + 0] = (a.x + b.x) * z;
        vals[4 * q4 + 1] = (a.y + b.y) * z;
        vals[4 * q4 + 2] = (a.z + b.z) * z;
        vals[4 * q4 + 3] = (a.w + b.w) * z;
    }
    if (*flag != 0.f) {
        uint4 o0, o1;
        o0.x = (unsigned)f2bf(vals[0]) | ((unsigned)f2bf(vals[1]) << 16);
        o0.y = (unsigned)f2bf(vals[2]) | ((unsigned)f2bf(vals[3]) << 16);
        o0.z = (unsigned)f2bf(vals[4]) | ((unsigned)f2bf(vals[5]) << 16);
        o0.w = (unsigned)f2bf(vals[6]) | ((unsigned)f2bf(vals[7]) << 16);
        o1.x = (unsigned)f2bf(vals[8]) | ((unsigned)f2bf(vals[9]) << 16);
        o1.y = (unsigned)f2bf(vals[10]) | ((unsigned)f2bf(vals[11]) << 16);
        o1.z = (unsigned)f2bf(vals[12]) | ((unsigned)f2bf(vals[13]) << 16);
        o1.w = (unsigned)f2bf(vals[14]) | ((unsigned)f2bf(vals[15]) << 16);
        unsigned short* op = (unsigned short*)outp + base;
        *(uint4*)op = o0;
        *(uint4*)(op + 8) = o1;
    } else {
        float* op = (float*)outp + base;
        #pragma unroll
        for (int q4 = 0; q4 < 4; ++q4)
            *(float4*)&op[4 * q4] = make_float4(vals[4 * q4], vals[4 * q4 + 1],
                                                vals[4 * q4 + 2], vals[4 * q4 + 3]);
    }
}

extern "C" void kernel_launch(void* const* d_in, const int* in_sizes, int n_in,
                              void* d_out, int out_size, void* d_ws, size_t ws_size,
                              hipStream_t stream) {
    const void* Q = d_in[0];
    const void* K = d_in[1];
    const void* V = d_in[2];
    const void* P = d_in[3];

    float* W = (float*)d_ws;
    float* flag = W;                                  // [16]
    float* c_k = W + 16;                              // [32768]
    float* c_q = c_k + 32768;                         // [32768]
    float* ksum01 = c_q + 32768;                      // [2][32768]; reused as pad
    float* kvf01 = ksum01 + 2 * RSPLIT;               // [2][16][64][2048] f32; reused as po
    float* ksumW = kvf01 + 2 * KVSPLIT;               // [32768]
    unsigned short* kvTW = (unsigned short*)(ksumW + RSPLIT);  // [16][64][2048] bf16

    LinearAttention_15985868276494_detect<<<1, 64, 0, stream>>>(
        (const unsigned short*)P, flag);
    LinearAttention_15985868276494_stats<<<dim3(512, 2), 256, 0, stream>>>(
        K, Q, P, flag, c_k, c_q);
    LinearAttention_15985868276494_kv<<<dim3(1024), 256, 37376, stream>>>(
        K, V, P, flag, c_k, kvf01, ksum01);
    LinearAttention_15985868276494_reduce<<<2048, 256, 0, stream>>>(
        kvf01, ksum01, kvTW, ksumW);
    LinearAttention_15985868276494_out<<<dim3(1024), 256, 37120, stream>>>(
        Q, P, flag, c_q, kvTW, ksumW, kvf01, ksum01);
    LinearAttention_15985868276494_out2<<<512, 256, 0, stream>>>(
        kvf01, ksum01, flag, d_out);
}

// Round 4
// 186.081 us; speedup vs baseline: 1.1776x; 1.1776x over previous
//
#include <hip/hip_runtime.h>

// Performer linear attention, 32x32x16 MFMA, register-resident features.
// n=2, l=2048, h=8, e=64, m=2048. Dtype runtime-detected (bf16 confirmed).
// ws (floats): flag[16] | c_k[32768] | c_q[32768] | ksum01[2][32768] (reused as pad[2][32768])
//   | kvf01[2][16][64][2048] f32 (reused as po[2][32768][64]) | ksumW[32768] | kvT bf16[16][64][2048]
// R10: multicast round. R7-R9 falsified occupancy/L2-locality/barrier-drain; arithmetic
//     shows per-iter wall 10.5k cy vs ~500 cy issue -> the 32-way same-line K/V tile
//     multicast (16 MB/iter lockstep burst) serializes at L2 banks (~3.7 TB/s effective).
//     Fix: 4x block merge (1024 thr, 16 waves) so each staged tile feeds 4x compute:
//     kv/out blocks own 256 m/l cols; P/Q/X fragments via direct global loads; epilogue
//     in 4 epochs over shared fin. Multicast burst 4x smaller; grid 256 = 1/CU.

#define LL 2048
#define HH 8
#define MM 2048
#define ROWSTR 512  // HH*64

#define NORMC 0.35355339059327373f   // 64^-0.25
#define LOG2E 1.4426950408889634f
#define NORMC2 (NORMC * LOG2E)
#define RATIO 0.022097086912079608f  // 2048^-0.5
#define KEPS 1e-4f
#define REPS (RATIO * KEPS)
#define EPSD 1e-6f

#define KVSPLIT 2097152
#define RSPLIT 32768

typedef __attribute__((ext_vector_type(8))) short short8;
typedef __attribute__((ext_vector_type(16))) float f32x16;

#define MFMA32(a, b, c) __builtin_amdgcn_mfma_f32_32x32x16_bf16((a), (b), (c), 0, 0, 0)

// LDS-only workgroup barrier: drains lgkmcnt but leaves global loads in flight.
__device__ __forceinline__ void wg_barrier_lds() {
    asm volatile("s_waitcnt lgkmcnt(0)" ::: "memory");
    __builtin_amdgcn_s_barrier();
    __builtin_amdgcn_sched_barrier(0);
}

__device__ __forceinline__ f32x16 zero16() {
    f32x16 v;
    #pragma unroll
    for (int i = 0; i < 16; ++i) v[i] = 0.f;
    return v;
}
__device__ __forceinline__ unsigned short f2bf(float f) {  // RNE
    union { float f; unsigned int u; } v; v.f = f;
    unsigned int r = v.u + 0x7fffu + ((v.u >> 16) & 1u);
    return (unsigned short)(r >> 16);
}
__device__ __forceinline__ unsigned int pk2(float lo, float hi) {  // trunc pack
    return __builtin_amdgcn_perm(__float_as_uint(hi), __float_as_uint(lo), 0x07060302u);
}
__device__ __forceinline__ float bf2f(unsigned short u) {
    union { unsigned int ui; float f; } v; v.ui = ((unsigned int)u) << 16; return v.f;
}

// ---- direct global row-fragment load: 8 bf16 at row*stride + off ----
template <bool BF16>
__device__ __forceinline__ short8 row_load8(const void* src, size_t rowbase, int off) {
    if (BF16) {
        return *(const short8*)((const unsigned short*)src + rowbase + off);
    } else {
        const float* p = (const float*)src + rowbase + off;
        float4 f0 = ((const float4*)p)[0], f1 = ((const float4*)p)[1];
        union { unsigned int u[4]; short8 s; } v;
        v.u[0] = pk2(f0.x, f0.y); v.u[1] = pk2(f0.z, f0.w);
        v.u[2] = pk2(f1.x, f1.y); v.u[3] = pk2(f1.z, f1.w);
        return v.s;
    }
}

// ---- 64x64 tile staging into LDS [64][72] bf16 (256-thread pattern) ----
template <bool BF16>
__device__ __forceinline__ void tile_load(const void* src, size_t base, size_t rstride,
                                          int t, uint4& A, uint4& B) {
    const int row = t >> 2, c16 = (t & 3) * 16;
    if (BF16) {
        const unsigned short* p = (const unsigned short*)src + base + (size_t)row * rstride + c16;
        A = *(const uint4*)p;
        B = *(const uint4*)(p + 8);
    } else {
        const float* p = (const float*)src + base + (size_t)row * rstride + c16;
        float4 f0 = ((const float4*)p)[0], f1 = ((const float4*)p)[1];
        float4 f2 = ((const float4*)p)[2], f3 = ((const float4*)p)[3];
        A.x = pk2(f0.x, f0.y); A.y = pk2(f0.z, f0.w);
        A.z = pk2(f1.x, f1.y); A.w = pk2(f1.z, f1.w);
        B.x = pk2(f2.x, f2.y); B.y = pk2(f2.z, f2.w);
        B.z = pk2(f3.x, f3.y); B.w = pk2(f3.z, f3.w);
    }
}
__device__ __forceinline__ void tile_store72(unsigned short* D, int t, uint4 A, uint4 B) {
    const int row = t >> 2, c16 = (t & 3) * 16;
    *(uint4*)&D[row * 72 + c16] = A;
    *(uint4*)&D[row * 72 + c16 + 8] = B;
}

// ---- V transpose staging into LDS [64e][72] (256-thread pattern) ----
template <bool BF16>
__device__ __forceinline__ void vt_load(const void* V, size_t base, int t, uint4& A, uint4& B) {
    const int s0 = (t & 31) * 2, e0 = (t >> 5) * 8;
    if (BF16) {
        const unsigned short* p = (const unsigned short*)V + base + (size_t)s0 * ROWSTR + e0;
        A = *(const uint4*)p;
        B = *(const uint4*)(p + ROWSTR);
    } else {
        const float* p = (const float*)V + base + (size_t)s0 * ROWSTR + e0;
        float4 f0 = ((const float4*)p)[0], f1 = ((const float4*)p)[1];
        const float* q = p + ROWSTR;
        float4 g0 = ((const float4*)q)[0], g1 = ((const float4*)q)[1];
        A.x = pk2(f0.x, f0.y); A.y = pk2(f0.z, f0.w);
        A.z = pk2(f1.x, f1.y); A.w = pk2(f1.z, f1.w);
        B.x = pk2(g0.x, g0.y); B.y = pk2(g0.z, g0.w);
        B.z = pk2(g1.x, g1.y); B.w = pk2(g1.z, g1.w);
    }
}
__device__ __forceinline__ void vt_store72(unsigned short* VT, int t, uint4 A, uint4 B) {
    const int s0 = (t & 31) * 2, e0 = (t >> 5) * 8;
    const unsigned ua[4] = {A.x, A.y, A.z, A.w}, ub[4] = {B.x, B.y, B.z, B.w};
    #pragma unroll
    for (int i = 0; i < 4; ++i) {
        *(unsigned*)&VT[(e0 + 2 * i) * 72 + s0] = (ua[i] & 0xFFFFu) | (ub[i] << 16);
        *(unsigned*)&VT[(e0 + 2 * i + 1) * 72 + s0] = (ua[i] >> 16) | (ub[i] & 0xFFFF0000u);
    }
}

// ---- D-layout -> B-operand exchange (half-wave) ----
__device__ __forceinline__ short8 xfrag(const unsigned int pd[8], int cp, int hi) {
    const unsigned int s0 = hi ? pd[4 * cp + 0] : pd[4 * cp + 2];
    const unsigned int s1 = hi ? pd[4 * cp + 1] : pd[4 * cp + 3];
    const unsigned int r0 = (unsigned int)__shfl_xor((int)s0, 32);
    const unsigned int r1 = (unsigned int)__shfl_xor((int)s1, 32);
    union { unsigned int u[4]; short8 s; } v;
    v.u[0] = hi ? r0 : pd[4 * cp + 0];
    v.u[1] = hi ? r1 : pd[4 * cp + 1];
    v.u[2] = hi ? pd[4 * cp + 2] : r0;
    v.u[3] = hi ? pd[4 * cp + 3] : r1;
    return v.s;
}

// ---------------- dtype detection ----------------
__global__ void LinearAttention_15985868276494_detect(const unsigned short* __restrict__ P,
                                                      float* __restrict__ flag) {
    if (threadIdx.x == 0) {
        int sane = 1;
        #pragma unroll
        for (int i = 0; i < 16; ++i) {
            const unsigned e = (P[2 * i] >> 7) & 0xFF;
            if (e < 101 || e > 141) sane = 0;
        }
        *flag = sane ? 1.0f : 0.0f;
    }
}

// ---------------- stats: c[nh][l]*log2e, 256 rows/block, stream 32 P-tiles ----------------
// 16 waves: mstrip = w&1 (m-half of 64-tile), rstrip = w>>1 in [0,8) (32-row chunk).
// X fragments direct from global; only P staged (waves 0-3).
template <bool BF16>
__device__ void stats_impl(const void* X, const void* P, float* cws,
                           unsigned short* Ps, float* red) {
    const int t = threadIdx.x;
    const int w = t >> 6, ln = t & 31, hi = (t >> 5) & 1;
    const int mstrip = w & 1, rstrip = w >> 1;
    const int row_base = blockIdx.x * 256;

    short8 xb[4];
    #pragma unroll
    for (int c = 0; c < 4; ++c)
        xb[c] = row_load8<BF16>(X, (size_t)(row_base + rstrip * 32 + ln) * 64, 16 * c + 8 * hi);

    const bool stP = (t < 256);
    const int tl = t & 255;
    uint4 pA, pB;
    if (stP) {
        uint4 a0, b0;
        tile_load<BF16>(P, 0, 64, tl, a0, b0);
        tile_store72(Ps, tl, a0, b0);
        tile_load<BF16>(P, (size_t)64 * 64, 64, tl, pA, pB);
    }
    wg_barrier_lds();

    float rmax = -3e38f;
    for (int i = 0; i < 32; ++i) {
        const int cur = i & 1;
        unsigned short* Pc = Ps + cur * 4608;
        f32x16 acc = zero16();
        #pragma unroll
        for (int c = 0; c < 4; ++c) {
            const short8 af = *(const short8*)&Pc[(32 * mstrip + ln) * 72 + 16 * c + 8 * hi];
            acc = MFMA32(af, xb[c], acc);
        }
        if (stP && i + 1 < 32) {
            tile_store72(Ps + (cur ^ 1) * 4608, tl, pA, pB);
            if (i + 2 < 32)
                tile_load<BF16>(P, (size_t)((i + 2) * 64) * 64, 64, tl, pA, pB);
        }
        #pragma unroll
        for (int r = 0; r < 16; ++r) rmax = fmaxf(rmax, acc[r]);
        wg_barrier_lds();
    }
    rmax = fmaxf(rmax, __shfl_xor(rmax, 32));
    if (hi == 0) red[w * 32 + ln] = rmax;
    // s2 from X registers (mstrip==0 waves own the write)
    float s2 = 0.f;
    if (mstrip == 0) {
        #pragma unroll
        for (int c = 0; c < 4; ++c) {
            union { short8 s; unsigned int u[4]; } uv; uv.s = xb[c];
            #pragma unroll
            for (int i2 = 0; i2 < 4; ++i2) {
                const float lo = bf2f((unsigned short)(uv.u[i2] & 0xFFFF));
                const float hv = bf2f((unsigned short)(uv.u[i2] >> 16));
                s2 = fmaf(lo, lo, s2); s2 = fmaf(hv, hv, s2);
            }
        }
        s2 += __shfl_xor(s2, 32);
    }
    wg_barrier_lds();
    if (mstrip == 0 && hi == 0) {
        const float rm = fmaxf(red[w * 32 + ln], red[(w + 1) * 32 + ln]);
        const int rg = row_base + rstrip * 32 + ln;
        const int n = rg >> 14, l = (rg >> 3) & 2047, h = rg & 7;
        cws[(size_t)((n << 3) | h) * LL + l] =
            (NORMC * rm + (0.5f * NORMC * NORMC) * s2) * LOG2E;
    }
}

__global__ __launch_bounds__(1024, 4) void LinearAttention_15985868276494_stats(
        const void* K, const void* Q, const void* P, const float* flag,
        float* c_k, float* c_q) {
    __shared__ unsigned short Ps[2 * 64 * 72];
    __shared__ float red[512];
    const void* X = (blockIdx.y == 0) ? K : Q;
    float* cws = (blockIdx.y == 0) ? c_k : c_q;
    if (*flag != 0.f) stats_impl<true>(X, P, cws, Ps, red);
    else stats_impl<false>(X, P, cws, Ps, red);
}

// ---------------- kv: partial kvf[sp][nh][e][m] f32, ksum01 ----------------
// 256 blocks x 1024 thr. Block owns 256 m-cols (mtb in [0,8)); streams 16 K/V s-tiles.
// 16 waves: w2=w&3 -> sstrip=w2&1, msub=w2>>1; epoch ep=w>>2; m-chunk mc=2*ep+msub.
// P fragments direct from global. XCD swizzle: g=(nh,sp) group, 8 blocks/group on 1 XCD.
// LDS: Ks[2][64*72] | VT[2][64*72] | cks[2][64]; fin[4*64*33] aliases Ks+VT.
template <bool BF16>
__device__ void kv_impl(const void* K, const void* V, const void* P, const float* cws,
                        float* kvf01, float* ksum01, char* smem) {
    unsigned short* Ks = (unsigned short*)smem;            // [2][64*72]
    unsigned short* VT = (unsigned short*)(smem + 18432);  // [2][64*72]
    float* cks = (float*)(smem + 36864);                   // [2][64]
    float* fin = (float*)smem;                             // [4*64*33]

    const int t = threadIdx.x;
    const int w = t >> 6, ln = t & 31, hi = (t >> 5) & 1;
    const int w2 = w & 3, ep = w >> 2;
    const int sstrip = w2 & 1, msub = w2 >> 1;
    const int mc = ep * 2 + msub;  // 32-m chunk in [0,8)
    // grid decode: bid = xcd + 8*(gq*8 + mtb), g = gq*8 + xcd
    const int bid = blockIdx.x;
    const int xcd = bid & 7, rr = bid >> 3;
    const int gq = rr >> 3, mtb = rr & 7;
    const int g = gq * 8 + xcd;
    const int nh = g >> 1, sp = g & 1;
    const int n = nh >> 3, h = nh & 7;
    const size_t xbase = (size_t)n * (LL * ROWSTR) + (size_t)h * 64;
    const int st0 = sp * 16;
    const int mbase = mtb * 256;

    const bool stK = (t < 256), stV = (t >= 256 && t < 512);
    const int tl = t & 255;

    // P fragments direct from global (rows m = mbase + mc*32 + ln)
    short8 pb[4];
    #pragma unroll
    for (int c = 0; c < 4; ++c)
        pb[c] = row_load8<BF16>(P, (size_t)(mbase + mc * 32 + ln) * 64, 16 * c + 8 * hi);

    uint4 kA, kB, vA, vB; float ckr = 0.f;
    if (stK) {
        tile_load<BF16>(K, xbase + (size_t)(st0 * 64) * ROWSTR, ROWSTR, tl, kA, kB);
        tile_store72(Ks, tl, kA, kB);
        tile_load<BF16>(K, xbase + (size_t)((st0 + 1) * 64) * ROWSTR, ROWSTR, tl, kA, kB);
    } else if (stV) {
        vt_load<BF16>(V, xbase + (size_t)(st0 * 64) * ROWSTR, tl, vA, vB);
        vt_store72(VT, tl, vA, vB);
        vt_load<BF16>(V, xbase + (size_t)((st0 + 1) * 64) * ROWSTR, tl, vA, vB);
    }
    if (t < 64) {
        cks[t] = cws[(size_t)nh * LL + st0 * 64 + t];
        ckr = cws[(size_t)nh * LL + (st0 + 1) * 64 + t];
    }
    wg_barrier_lds();

    const short8 ones = {0x3F80, 0x3F80, 0x3F80, 0x3F80, 0x3F80, 0x3F80, 0x3F80, 0x3F80};
    f32x16 akv0 = zero16(), akv1 = zero16(), aks = zero16();

    for (int i = 0; i < 16; ++i) {
        const int cur = i & 1;
        unsigned short* Kc = Ks + cur * 4608;
        unsigned short* Vc = VT + cur * 4608;
        const float* cc = cks + cur * 64;
        // gemm1: D[s][m] = K . P^T
        f32x16 D = zero16();
        #pragma unroll
        for (int c = 0; c < 4; ++c) {
            const short8 af = *(const short8*)&Kc[(32 * sstrip + ln) * 72 + 16 * c + 8 * hi];
            D = MFMA32(af, pb[c], D);
        }
        // staging: store tile i+1, prefetch tile i+2
        if (i + 1 < 16) {
            if (stK) tile_store72(Ks + (cur ^ 1) * 4608, tl, kA, kB);
            else if (stV) vt_store72(VT + (cur ^ 1) * 4608, tl, vA, vB);
            if (t < 64) cks[(cur ^ 1) * 64 + t] = ckr;
            if (i + 2 < 16) {
                const int st = st0 + i + 2;
                if (stK) tile_load<BF16>(K, xbase + (size_t)(st * 64) * ROWSTR, ROWSTR, tl, kA, kB);
                else if (stV) vt_load<BF16>(V, xbase + (size_t)(st * 64) * ROWSTR, tl, vA, vB);
                if (t < 64) ckr = cws[(size_t)nh * LL + st * 64 + t];
            }
        }
        // exp2 (c pre-scaled by log2e; varies with s = row)
        unsigned int pd[8];
        #pragma unroll
        for (int gIdx = 0; gIdx < 4; ++gIdx) {
            const float4 c4 = *(const float4*)&cc[32 * sstrip + 8 * gIdx + 4 * hi];
            const float ca[4] = {c4.x, c4.y, c4.z, c4.w};
            float f[4];
            #pragma unroll
            for (int b = 0; b < 4; ++b) {
                const float arg = fminf(fmaf(D[4 * gIdx + b], NORMC2, -ca[b]), 0.f);
                f[b] = fmaf(__builtin_amdgcn_exp2f(arg), RATIO, REPS);
            }
            pd[2 * gIdx] = pk2(f[0], f[1]);
            pd[2 * gIdx + 1] = pk2(f[2], f[3]);
        }
        // gemm2: akv[e][m] += V^T . F
        #pragma unroll
        for (int cp = 0; cp < 2; ++cp) {
            const short8 bf = xfrag(pd, cp, hi);
            const int scol = 32 * sstrip + 16 * cp + 8 * hi;
            const short8 v0 = *(const short8*)&Vc[ln * 72 + scol];
            const short8 v1 = *(const short8*)&Vc[(32 + ln) * 72 + scol];
            akv0 = MFMA32(v0, bf, akv0);
            akv1 = MFMA32(v1, bf, akv1);
            aks = MFMA32(ones, bf, aks);
        }
        wg_barrier_lds();
    }
    // epilogue: 4 epochs, each = one 64-m tile handled by its 4 waves via fin
    #pragma unroll 1
    for (int e4 = 0; e4 < 4; ++e4) {
        if (ep == e4) {
            const int slot = (w2 * 64 + (t & 63)) * 33;
            #pragma unroll
            for (int r = 0; r < 16; ++r) fin[slot + r] = akv0[r];
            #pragma unroll
            for (int r = 0; r < 16; ++r) fin[slot + 16 + r] = akv1[r];
            fin[slot + 32] = aks[0];
        }
        wg_barrier_lds();
        if (ep == e4) {
            const int tt = t & 255;
            const int mt = mtb * 4 + e4;
            const int e = tt >> 2;
            const int t16 = e >> 5, e5 = e & 31;
            const int hi_s = (e5 >> 2) & 1;
            const int reg = 16 * t16 + (e5 & 3) + 4 * (e5 >> 3);
            float* dst = kvf01 + (size_t)sp * KVSPLIT + (size_t)nh * (64 * MM)
                       + (size_t)e * MM + mt * 64 + (tt & 3) * 16;
            #pragma unroll
            for (int jq = 0; jq < 4; ++jq) {
                float o[4];
                #pragma unroll
                for (int b = 0; b < 4; ++b) {
                    const int m_local = (tt & 3) * 16 + 4 * jq + b;
                    const int ms = m_local >> 5;
                    const int lane_s = hi_s * 32 + (m_local & 31);
                    o[b] = fin[((2 * ms) * 64 + lane_s) * 33 + reg]
                         + fin[((2 * ms + 1) * 64 + lane_s) * 33 + reg];
                }
                *(float4*)&dst[4 * jq] = make_float4(o[0], o[1], o[2], o[3]);
            }
            if (tt < 64) {
                const int ms = tt >> 5;
                const float val = fin[((2 * ms) * 64 + (tt & 31)) * 33 + 32]
                                + fin[((2 * ms + 1) * 64 + (tt & 31)) * 33 + 32];
                ksum01[(size_t)sp * RSPLIT + (size_t)nh * MM + mt * 64 + tt] = val;
            }
        }
        wg_barrier_lds();
    }
}

__global__ __launch_bounds__(1024, 4) void LinearAttention_15985868276494_kv(
        const void* K, const void* V, const void* P, const float* flag,
        const float* cws, float* kvf01, float* ksum01) {
    extern __shared__ char smem_kv[];
    if (*flag != 0.f) kv_impl<true>(K, V, P, cws, kvf01, ksum01, smem_kv);
    else kv_impl<false>(K, V, P, cws, kvf01, ksum01, smem_kv);
}

// ---------------- reduce: kvT bf16 = split0+split1; ksumW ----------------
__global__ __launch_bounds__(256) void LinearAttention_15985868276494_reduce(
        const float* __restrict__ kvf01, const float* __restrict__ ksum01,
        unsigned short* __restrict__ kvT, float* __restrict__ ksumW) {
    const int gid = blockIdx.x * 256 + threadIdx.x;
    const size_t i4 = (size_t)gid * 4;
    const float4 a = *(const float4*)&kvf01[i4];
    const float4 b = *(const float4*)&kvf01[KVSPLIT + i4];
    uint2 o;
    o.x = (unsigned)f2bf(a.x + b.x) | ((unsigned)f2bf(a.y + b.y) << 16);
    o.y = (unsigned)f2bf(a.z + b.z) | ((unsigned)f2bf(a.w + b.w) << 16);
    *(uint2*)&kvT[i4] = o;
    if (blockIdx.x < 32) {
        const float4 c = *(const float4*)&ksum01[i4];
        const float4 d = *(const float4*)&ksum01[RSPLIT + i4];
        *(float4*)&ksumW[i4] = make_float4(c.x + d.x, c.y + d.y, c.z + d.z, c.w + d.w);
    }
}

// ---------------- out (partial over m-half sp): po f32, pad f32 ----------------
// 256 blocks x 1024 thr. Block owns 256 l-rows (lbb in [0,8)); streams 16 m-tiles.
// 16 waves: w2=w&3 -> mstrip=w2&1, lsub=w2>>1; epoch ep=w>>2; l-chunk lc=2*ep+lsub.
// Q fragments direct from global. LDS: Ps[2][64*72] | KVs[2][64*72] | kss[2][64]; fin aliases.
template <bool BF16>
__device__ void out_impl(const void* Q, const void* P, const float* cqw,
                         const unsigned short* kvT, const float* ksum,
                         float* po, float* pad, char* smem) {
    unsigned short* Ps = (unsigned short*)smem;              // [2][64*72]
    unsigned short* KVs = (unsigned short*)(smem + 18432);   // [2][64*72]
    unsigned short* kss = (unsigned short*)(smem + 36864);   // [2][64]
    float* fin = (float*)smem;                               // [4*64*33]

    const int t = threadIdx.x;
    const int w = t >> 6, ln = t & 31, hi = (t >> 5) & 1;
    const int w2 = w & 3, ep = w >> 2;
    const int mstrip = w2 & 1, lsub = w2 >> 1;
    const int lc = ep * 2 + lsub;  // 32-l chunk in [0,8)
    // grid decode
    const int bid = blockIdx.x;
    const int xcd = bid & 7, rr = bid >> 3;
    const int gq = rr >> 3, lbb = rr & 7;
    const int g = gq * 8 + xcd;
    const int nh = g >> 1, sp = g & 1;
    const int n = nh >> 3, h = nh & 7;
    const size_t qbase = (size_t)n * (LL * ROWSTR) + (size_t)h * 64;
    const size_t kvbase = (size_t)nh * (size_t)(64 * MM);
    const int mt0 = sp * 16;
    const int lbase = lbb * 256;

    const bool stP = (t < 256), stKV = (t >= 256 && t < 512);
    const int tl = t & 255;

    // Q fragments direct from global (rows l = lbase + lc*32 + ln)
    short8 qb[4];
    #pragma unroll
    for (int c = 0; c < 4; ++c)
        qb[c] = row_load8<BF16>(Q, qbase + (size_t)(lbase + lc * 32 + ln) * ROWSTR, 16 * c + 8 * hi);
    const float cq = cqw[(size_t)nh * LL + lbase + lc * 32 + ln];

    uint4 pA, pB, kA, kB; float ksr = 0.f;
    if (stP) {
        tile_load<BF16>(P, (size_t)(mt0 * 64) * 64, 64, tl, pA, pB);
        tile_store72(Ps, tl, pA, pB);
        tile_load<BF16>(P, (size_t)((mt0 + 1) * 64) * 64, 64, tl, pA, pB);
    } else if (stKV) {
        tile_load<true>(kvT, kvbase + mt0 * 64, MM, tl, kA, kB);
        tile_store72(KVs, tl, kA, kB);
        tile_load<true>(kvT, kvbase + (mt0 + 1) * 64, MM, tl, kA, kB);
    }
    if (t < 64) {
        kss[t] = f2bf(ksum[(size_t)nh * MM + mt0 * 64 + t]);
        ksr = ksum[(size_t)nh * MM + (mt0 + 1) * 64 + t];
    }
    wg_barrier_lds();

    f32x16 ao0 = zero16(), ao1 = zero16(), ad = zero16();

    for (int i = 0; i < 16; ++i) {
        const int cur = i & 1;
        unsigned short* Pc = Ps + cur * 4608;
        unsigned short* Kc = KVs + cur * 4608;
        const unsigned short* ksc = kss + cur * 64;
        // gemm1: D[m][l] = P . Q^T
        f32x16 D = zero16();
        #pragma unroll
        for (int c = 0; c < 4; ++c) {
            const short8 af = *(const short8*)&Pc[(32 * mstrip + ln) * 72 + 16 * c + 8 * hi];
            D = MFMA32(af, qb[c], D);
        }
        // staging
        if (i + 1 < 16) {
            if (stP) tile_store72(Ps + (cur ^ 1) * 4608, tl, pA, pB);
            else if (stKV) tile_store72(KVs + (cur ^ 1) * 4608, tl, kA, kB);
            if (t < 64) kss[(cur ^ 1) * 64 + t] = f2bf(ksr);
            if (i + 2 < 16) {
                if (stP) tile_load<BF16>(P, (size_t)((mt0 + i + 2) * 64) * 64, 64, tl, pA, pB);
                else if (stKV) tile_load<true>(kvT, kvbase + (mt0 + i + 2) * 64, MM, tl, kA, kB);
                if (t < 64) ksr = ksum[(size_t)nh * MM + (mt0 + i + 2) * 64 + t];
            }
        }
        // exp2 (cq depends on l = col only)
        unsigned int pd[8];
        #pragma unroll
        for (int gIdx = 0; gIdx < 4; ++gIdx) {
            float f[4];
            #pragma unroll
            for (int b = 0; b < 4; ++b) {
                const float arg = fminf(fmaf(D[4 * gIdx + b], NORMC2, -cq), 0.f);
                f[b] = fmaf(__builtin_amdgcn_exp2f(arg), RATIO, REPS);
            }
            pd[2 * gIdx] = pk2(f[0], f[1]);
            pd[2 * gIdx + 1] = pk2(f[2], f[3]);
        }
        // gemm2: O[e][l] += KV . F ; ad[.][l] += ksum . F
        #pragma unroll
        for (int cp = 0; cp < 2; ++cp) {
            const short8 bf = xfrag(pd, cp, hi);
            const int mcol = 32 * mstrip + 16 * cp + 8 * hi;
            const short8 a0 = *(const short8*)&Kc[ln * 72 + mcol];
            const short8 a1 = *(const short8*)&Kc[(32 + ln) * 72 + mcol];
            const short8 k8 = *(const short8*)&ksc[mcol];
            ao0 = MFMA32(a0, bf, ao0);
            ao1 = MFMA32(a1, bf, ao1);
            ad = MFMA32(k8, bf, ad);
        }
        wg_barrier_lds();
    }
    // epilogue: 4 epochs, each = one 64-l tile
    #pragma unroll 1
    for (int e4 = 0; e4 < 4; ++e4) {
        if (ep == e4) {
            const int slot = (w2 * 64 + (t & 63)) * 33;
            #pragma unroll
            for (int r = 0; r < 16; ++r) fin[slot + r] = ao0[r];
            #pragma unroll
            for (int r = 0; r < 16; ++r) fin[slot + 16 + r] = ao1[r];
            fin[slot + 32] = ad[0];
        }
        wg_barrier_lds();
        if (ep == e4) {
            const int tt = t & 255;
            const int l_local = tt >> 2, eg = tt & 3;
            const int ls = l_local >> 5, lane_l = l_local & 31;
            const float adt = fin[((2 * ls) * 64 + lane_l) * 33 + 32]
                            + fin[((2 * ls + 1) * 64 + lane_l) * 33 + 32];
            const int l = (lbb * 4 + e4) * 64 + l_local;
            const size_t row = (size_t)(n * LL + l) * HH + h;
            if (eg == 0) pad[(size_t)sp * RSPLIT + row] = adt;
            float* dst = po + (size_t)sp * KVSPLIT + row * 64 + eg * 16;
            #pragma unroll
            for (int jq = 0; jq < 4; ++jq) {
                float o[4];
                #pragma unroll
                for (int b = 0; b < 4; ++b) {
                    const int e = eg * 16 + 4 * jq + b;
                    const int t16 = e >> 5, e5 = e & 31;
                    const int hi_s = (e5 >> 2) & 1;
                    const int reg = 16 * t16 + (e5 & 3) + 4 * (e5 >> 3);
                    const int lane_s = hi_s * 32 + lane_l;
                    o[b] = fin[((2 * ls) * 64 + lane_s) * 33 + reg]
                         + fin[((2 * ls + 1) * 64 + lane_s) * 33 + reg];
                }
                *(float4*)&dst[4 * jq] = make_float4(o[0], o[1], o[2], o[3]);
            }
        }
        wg_barrier_lds();
    }
}

__global__ __launch_bounds__(1024, 4) void LinearAttention_15985868276494_out(
        const void* Q, const void* P, const float* flag, const float* cqw,
        const unsigned short* kvT, const float* ksum, float* po, float* pad) {
    extern __shared__ char smem_out[];
    if (*flag != 0.f) out_impl<true>(Q, P, cqw, kvT, ksum, po, pad, smem_out);
    else out_impl<false>(Q, P, cqw, kvT, ksum, po, pad, smem_out);
}

// ---------------- out2: combine m-halves, normalize, emit ----------------
__global__ __launch_bounds__(256) void LinearAttention_15985868276494_out2(
        const float* __restrict__ po, const float* __restrict__ pad,
        const float* __restrict__ flag, void* __restrict__ outp) {
    const int gid = blockIdx.x * 256 + threadIdx.x;
    const int row = gid >> 2, eg = gid & 3;
    const float adt = pad[row] + pad[RSPLIT + row];
    const float z = 1.0f / (adt + EPSD);
    const size_t base = (size_t)row * 64 + eg * 16;
    float vals[16];
    #pragma unroll
    for (int q4 = 0; q4 < 4; ++q4) {
        const float4 a = *(const float4*)&po[base + 4 * q4];
        const float4 b = *(const float4*)&po[KVSPLIT + base + 4 * q4];
        vals[4 * q4 + 0] = (a.x + b.x) * z;
        vals[4 * q4 + 1] = (a.y + b.y) * z;
        vals[4 * q4 + 2] = (a.z + b.z) * z;
        vals[4 * q4 + 3] = (a.w + b.w) * z;
    }
    if (*flag != 0.f) {
        uint4 o0, o1;
        o0.x = (unsigned)f2bf(vals[0]) | ((unsigned)f2bf(vals[1]) << 16);
        o0.y = (unsigned)f2bf(vals[2]) | ((unsigned)f2bf(vals[3]) << 16);
        o0.z = (unsigned)f2bf(vals[4]) | ((unsigned)f2bf(vals[5]) << 16);
        o0.w = (unsigned)f2bf(vals[6]) | ((unsigned)f2bf(vals[7]) << 16);
        o1.x = (unsigned)f2bf(vals[8]) | ((unsigned)f2bf(vals[9]) << 16);
        o1.y = (unsigned)f2bf(vals[10]) | ((unsigned)f2bf(vals[11]) << 16);
        o1.z = (unsigned)f2bf(vals[12]) | ((unsigned)f2bf(vals[13]) << 16);
        o1.w = (unsigned)f2bf(vals[14]) | ((unsigned)f2bf(vals[15]) << 16);
        unsigned short* op = (unsigned short*)outp + base;
        *(uint4*)op = o0;
        *(uint4*)(op + 8) = o1;
    } else {
        float* op = (float*)outp + base;
        #pragma unroll
        for (int q4 = 0; q4 < 4; ++q4)
            *(float4*)&op[4 * q4] = make_float4(vals[4 * q4], vals[4 * q4 + 1],
                                                vals[4 * q4 + 2], vals[4 * q4 + 3]);
    }
}

extern "C" void kernel_launch(void* const* d_in, const int* in_sizes, int n_in,
                              void* d_out, int out_size, void* d_ws, size_t ws_size,
                              hipStream_t stream) {
    const void* Q = d_in[0];
    const void* K = d_in[1];
    const void* V = d_in[2];
    const void* P = d_in[3];

    float* W = (float*)d_ws;
    float* flag = W;                                  // [16]
    float* c_k = W + 16;                              // [32768]
    float* c_q = c_k + 32768;                         // [32768]
    float* ksum01 = c_q + 32768;                      // [2][32768]; reused as pad
    float* kvf01 = ksum01 + 2 * RSPLIT;               // [2][16][64][2048] f32; reused as po
    float* ksumW = kvf01 + 2 * KVSPLIT;               // [32768]
    unsigned short* kvTW = (unsigned short*)(ksumW + RSPLIT);  // [16][64][2048] bf16

    LinearAttention_15985868276494_detect<<<1, 64, 0, stream>>>(
        (const unsigned short*)P, flag);
    LinearAttention_15985868276494_stats<<<dim3(128, 2), 1024, 0, stream>>>(
        K, Q, P, flag, c_k, c_q);
    LinearAttention_15985868276494_kv<<<dim3(256), 1024, 37376, stream>>>(
        K, V, P, flag, c_k, kvf01, ksum01);
    LinearAttention_15985868276494_reduce<<<2048, 256, 0, stream>>>(
        kvf01, ksum01, kvTW, ksumW);
    LinearAttention_15985868276494_out<<<dim3(256), 1024, 37120, stream>>>(
        Q, P, flag, c_q, kvTW, ksumW, kvf01, ksum01);
    LinearAttention_15985868276494_out2<<<512, 256, 0, stream>>>(
        kvf01, ksum01, flag, d_out);
}